// Round 6
// baseline (317.696 us; speedup 1.0000x reference)
//
#include <hip/hip_runtime.h>
#include <hip/hip_bf16.h>
#include <cstdint>

#define IN_SZ 50000
#define NM 3
#define N0 40960
#define N1 16384
#define NB 4096
#define HD 256
#define DEG 16
#define E0 (N1*DEG)
#define E1 (NB*DEG)

using short8v = __attribute__((ext_vector_type(8))) short;
using floatx4 = __attribute__((ext_vector_type(4))) float;
typedef unsigned short ushort_t;

__device__ __forceinline__ ushort_t f2bf(float f){
  uint32_t u = __float_as_uint(f);
  uint32_t r = u + 0x7FFFu + ((u>>16)&1u);
  return (ushort_t)(r>>16);
}
__device__ __forceinline__ float bf2f(ushort_t h){
  return __uint_as_float(((uint32_t)h)<<16);
}
__device__ __forceinline__ void gload_lds16(const ushort_t* g, ushort_t* l){
  __builtin_amdgcn_global_load_lds(
      (const __attribute__((address_space(1))) void*)g,
      (__attribute__((address_space(3))) void*)l, 16, 0, 0);
}

// ---------------- threefry2x32 (JAX-exact) ----------------
__device__ __forceinline__ uint32_t rotl32(uint32_t x, uint32_t d){ return (x<<d)|(x>>(32u-d)); }

__device__ void tf2x32(uint32_t k0, uint32_t k1, uint32_t c0, uint32_t c1,
                       uint32_t& y0, uint32_t& y1)
{
  uint32_t ks2 = k0 ^ k1 ^ 0x1BD11BDAu;
  uint32_t x0 = c0 + k0, x1 = c1 + k1;
#define R4(a,b,c,d) \
  x0+=x1; x1=rotl32(x1,a); x1^=x0; \
  x0+=x1; x1=rotl32(x1,b); x1^=x0; \
  x0+=x1; x1=rotl32(x1,c); x1^=x0; \
  x0+=x1; x1=rotl32(x1,d); x1^=x0;
  R4(13,15,26,6)  x0+=k1;  x1+=ks2+1u;
  R4(17,29,16,24) x0+=ks2; x1+=k0+2u;
  R4(13,15,26,6)  x0+=k0;  x1+=k1+3u;
  R4(17,29,16,24) x0+=k1;  x1+=ks2+4u;
  R4(13,15,26,6)  x0+=ks2; x1+=k0+5u;
#undef R4
  y0=x0; y1=x1;
}

__global__ void interp_coef_k(const float* __restrict__ masks, const float* __restrict__ sp,
                              float* __restrict__ coef, float* __restrict__ scales_out)
{
  int b = blockIdx.x*256 + threadIdx.x;
  if (b >= NB) return;
  float s0=sp[0], s1=sp[1], s2=sp[2];
  float mx = fmaxf(s0,fmaxf(s1,s2));
  float e0=expf(s0-mx), e1=expf(s1-mx), e2=expf(s2-mx);
  float inv = 1.f/(e0+e1+e2);
  float sc[3] = {e0*inv, e1*inv, e2*inv};
  if (b == 0){ scales_out[0]=sc[0]; scales_out[1]=sc[1]; scales_out[2]=sc[2]; }

  uint32_t bits[3];
  uint32_t K0,K1, t0,t1;
  tf2x32(0u,42u,0u,1u,K0,K1);
  for (int i=0;i<3;i++){
    uint32_t idx = (uint32_t)(b*3+i);
    tf2x32(K0,K1,0u,idx,t0,t1);
    bits[i] = (t0 ^ t1) & 1u;
  }
  float mk[3] = {masks[b*3+0], masks[b*3+1], masks[b*3+2]};
  float msum = mk[0]+mk[1]+mk[2];
  float rs = (float)(bits[0]+bits[1]+bits[2]);
  float add = powf(1.f/(1.f+rs), 20.f) + powf(1.f/msum, 20.f);
  float lg[3]; float lmax = -1e30f;
  for (int i=0;i<3;i++){
    float rm = floorf((float)bits[i] + add);
    rm = rm/(rm+1e-10f);
    float mm = mk[i]*rm;
    lg[i] = mm + (1.f-mm)*(-1e10f);
    lmax = fmaxf(lmax, lg[i]);
  }
  float es[3], ssum=0.f;
  for (int i=0;i<3;i++){ es[i]=expf(lg[i]-lmax); ssum+=es[i]; }
  for (int i=0;i<3;i++) coef[b*3+i] = sc[i]*es[i]/ssum;
}

// ---- elementwise hi/lo split (gat_W) ----
__global__ void split_k(const float* __restrict__ src, ushort_t* __restrict__ hi,
                        ushort_t* __restrict__ lo, int n)
{
  int g = blockIdx.x*256 + threadIdx.x;
  if (g >= n) return;
  float v = src[g];
  ushort_t h = f2bf(v);
  hi[g] = h;
  lo[g] = f2bf(v - bf2f(h));
}

// ---- bias prep: bias2 = pre_b . gat_W^T; bsum = bias2 + gat_b; batt = bias2 . att (per head)
__global__ void bias_prep_k(const float* __restrict__ pre_b, const float* __restrict__ gat_W,
                            const float* __restrict__ gat_att, const float* __restrict__ gat_b,
                            float* __restrict__ bsum, float* __restrict__ batt)
{
  int i = blockIdx.x, o = threadIdx.x;
  const float* W = gat_W + (size_t)i*HD*HD + (size_t)o*HD;
  const float* b = pre_b + i*HD;
  float s = 0.f;
  for (int k=0;k<HD;k++) s = fmaf(b[k], W[k], s);
  bsum[i*HD + o] = s + gat_b[i*HD + o];
  __shared__ float red[256];
  red[o] = s * gat_att[i*HD + o];
  __syncthreads();
  if (o < 4){
    float p = 0.f;
    for (int j=0;j<64;j++) p += red[o*64 + j];
    batt[i*4 + o] = p;
  }
}

// ---- GT GEMM: GT[c,o] = sum_k preW[k,c] * gatW[o,k]   (c: 50000, o: 256, k: 256)
// A read coalesced from preW (fp32), transposed to MFMA frag order via LDS.
// 2-term W split. Fused epilogue: alphaG[c,h] = leaky(GTacc . att + batt[h]).
__global__ __launch_bounds__(256) void gt_gemm(
    const float* __restrict__ preW_b,
    const ushort_t* __restrict__ Whi_b, const ushort_t* __restrict__ Wlo_b,
    const float* __restrict__ att_b, const float* __restrict__ batt,
    ushort_t* __restrict__ GT_b, float* __restrict__ alphaG_b)
{
  int i = blockIdx.z;
  int brow = blockIdx.x * 128;                      // c-offset
  const float* pw = preW_b + (size_t)i*HD*IN_SZ;
  const float* att = att_b + (size_t)i*HD;
  ushort_t* GT = GT_b + (size_t)i*IN_SZ*HD;
  float* alphaG = alphaG_b + (size_t)i*IN_SZ*4;

  __shared__ __align__(16) ushort_t As[2][4096];    // 8 rt x 64 lane x 8
  __shared__ __align__(16) ushort_t Bs[2][16384];   // 32 frag x 512

  int t = threadIdx.x, wave = t>>6, lane = t&63;
  int l15 = lane&15, kq = lane>>4;

  // B gload sources: fragment f = wave + 4*j -> ct=f>>1, hs=f&1
  const ushort_t* bsrc[8];
#pragma unroll
  for (int j=0;j<8;j++){
    int f = wave + 4*j, ct = f>>1, hs = f&1;
    const ushort_t* W = (hs ? Wlo_b : Whi_b) + (size_t)i*HD*HD;
    bsrc[j] = W + (size_t)(ct*16 + l15)*HD + kq*8;
  }
  // A-load assignment: f = t + 256*s -> c_local = f&127, q = f>>7
  int cl0 = t & 127, q0 = t >> 7;
  int cl1 = cl0, q1 = q0 + 2;
  int cg0 = brow + cl0; if (cg0 >= IN_SZ) cg0 = IN_SZ-1;
  int cg1 = brow + cl1; if (cg1 >= IN_SZ) cg1 = IN_SZ-1;
  int aoff0 = (cl0>>4)*512 + ((cl0&15) + q0*16)*8;
  int aoff1 = (cl1>>4)*512 + ((cl1&15) + q1*16)*8;

  floatx4 acc[2][16];
#pragma unroll
  for (int r=0;r<2;r++)
#pragma unroll
    for (int ct=0;ct<16;ct++) acc[r][ct] = (floatx4){0.f,0.f,0.f,0.f};

  // prologue: stage chunk 0
  {
    short8v v0, v1;
#pragma unroll
    for (int j=0;j<8;j++){
      v0[j] = (short)f2bf(pw[(size_t)(q0*8+j)*IN_SZ + cg0]);
      v1[j] = (short)f2bf(pw[(size_t)(q1*8+j)*IN_SZ + cg1]);
    }
    *reinterpret_cast<short8v*>(&As[0][aoff0]) = v0;
    *reinterpret_cast<short8v*>(&As[0][aoff1]) = v1;
#pragma unroll
    for (int j=0;j<8;j++) gload_lds16(bsrc[j], &Bs[0][(wave+4*j)*512]);
  }
  __syncthreads();

  for (int cc=0; cc<8; cc++){
    int buf = cc & 1;
    float an0[8], an1[8];
    if (cc < 7){
      int k0 = (cc+1)*32;
#pragma unroll
      for (int j=0;j<8;j++){
        an0[j] = pw[(size_t)(k0+q0*8+j)*IN_SZ + cg0];
        an1[j] = pw[(size_t)(k0+q1*8+j)*IN_SZ + cg1];
      }
#pragma unroll
      for (int j=0;j<8;j++) gload_lds16(bsrc[j]+k0, &Bs[buf^1][(wave+4*j)*512]);
    }
    short8v a0 = *reinterpret_cast<const short8v*>(&As[buf][(2*wave)*512 + lane*8]);
    short8v a1 = *reinterpret_cast<const short8v*>(&As[buf][(2*wave+1)*512 + lane*8]);
#pragma unroll
    for (int ct=0;ct<16;ct++){
      short8v bh = *reinterpret_cast<const short8v*>(&Bs[buf][(ct*2)*512 + lane*8]);
      short8v bl = *reinterpret_cast<const short8v*>(&Bs[buf][(ct*2+1)*512 + lane*8]);
      acc[0][ct] = __builtin_amdgcn_mfma_f32_16x16x32_bf16(a0, bh, acc[0][ct], 0,0,0);
      acc[0][ct] = __builtin_amdgcn_mfma_f32_16x16x32_bf16(a0, bl, acc[0][ct], 0,0,0);
      acc[1][ct] = __builtin_amdgcn_mfma_f32_16x16x32_bf16(a1, bh, acc[1][ct], 0,0,0);
      acc[1][ct] = __builtin_amdgcn_mfma_f32_16x16x32_bf16(a1, bl, acc[1][ct], 0,0,0);
    }
    if (cc < 7){
      short8v v0, v1;
#pragma unroll
      for (int j=0;j<8;j++){ v0[j] = (short)f2bf(an0[j]); v1[j] = (short)f2bf(an1[j]); }
      *reinterpret_cast<short8v*>(&As[buf^1][aoff0]) = v0;
      *reinterpret_cast<short8v*>(&As[buf^1][aoff1]) = v1;
    }
    __syncthreads();
  }

  // epilogue
  float attv[16];
#pragma unroll
  for (int ct=0;ct<16;ct++) attv[ct] = att[ct*16 + l15];
#pragma unroll
  for (int r=0;r<2;r++){
    int rbase = brow + (2*wave+r)*16 + kq*4;
#pragma unroll
    for (int j=0;j<4;j++){
      int c = rbase + j;
      bool ok = c < IN_SZ;
      size_t rw = (size_t)c*HD;
      if (ok){
#pragma unroll
        for (int ct=0;ct<16;ct++) GT[rw + ct*16 + l15] = f2bf(acc[r][ct][j]);
      }
#pragma unroll
      for (int h=0;h<4;h++){
        float p = acc[r][4*h+0][j]*attv[4*h+0] + acc[r][4*h+1][j]*attv[4*h+1]
                + acc[r][4*h+2][j]*attv[4*h+2] + acc[r][4*h+3][j]*attv[4*h+3];
        p += __shfl_xor(p, 1, 64);
        p += __shfl_xor(p, 2, 64);
        p += __shfl_xor(p, 4, 64);
        p += __shfl_xor(p, 8, 64);
        if (l15 == 0 && ok){
          p += batt[i*4 + h];
          alphaG[(size_t)c*4 + h] = p > 0.f ? p : 0.2f*p;
        }
      }
    }
  }
}

// ---- MFMA GEMM (layer 1): 128x128 tile, 2-term; fused leaky'd alpha epilogue ----
__global__ __launch_bounds__(256) void gemm2(
    const ushort_t* __restrict__ A_b, size_t a_stride,
    const ushort_t* __restrict__ Whi_b, const ushort_t* __restrict__ Wlo_b,
    ushort_t* __restrict__ C_b, size_t c_stride,
    const float* __restrict__ att_b, float* __restrict__ alpha_b, size_t al_stride)
{
  int i = blockIdx.z;
  int bn0 = blockIdx.y * 128;
  int brow = blockIdx.x * 128;
  const ushort_t* A = A_b + (size_t)i*a_stride;
  const ushort_t* Whi = Whi_b + (size_t)i*HD*HD;
  const ushort_t* Wlo = Wlo_b + (size_t)i*HD*HD;
  ushort_t* C = C_b + (size_t)i*c_stride;
  const float* att = att_b + (size_t)i*HD;
  float* alpha = alpha_b + (size_t)i*al_stride;

  __shared__ __align__(16) ushort_t smem[2][24*512];
  int t = threadIdx.x, wave = t>>6, lane = t&63;
  int l15 = lane&15, kq = lane>>4;

  int row0 = brow + wave*16 + l15;
  int row1 = brow + (wave+4)*16 + l15;

  const ushort_t* gsrc[6];
  gsrc[0] = A + (size_t)row0*HD + kq*8;
  gsrc[1] = A + (size_t)row1*HD + kq*8;
#pragma unroll
  for (int j=2;j<6;j++){
    int idx = wave + 4*(j-2);
    int ct = idx>>1, h = idx&1;
    const ushort_t* W = h ? Wlo : Whi;
    gsrc[j] = W + (size_t)(bn0 + ct*16 + l15)*HD + kq*8;
  }

  floatx4 acc[4][4];
#pragma unroll
  for (int r=0;r<4;r++)
#pragma unroll
    for (int c=0;c<4;c++) acc[r][c] = (floatx4){0.f,0.f,0.f,0.f};

  int wm = wave>>1, wn = wave&1;

#pragma unroll
  for (int j=0;j<6;j++)
    gload_lds16(gsrc[j], &smem[0][(wave + 4*j)*512]);
  __syncthreads();

  for (int cc=0; cc<8; cc++){
    int buf = cc & 1;
    if (cc < 7){
      int k0 = (cc+1)*32;
#pragma unroll
      for (int j=0;j<6;j++)
        gload_lds16(gsrc[j] + k0, &smem[buf^1][(wave + 4*j)*512]);
    }
    short8v a[4];
#pragma unroll
    for (int r=0;r<4;r++)
      a[r] = *reinterpret_cast<const short8v*>(&smem[buf][(wm*4+r)*512 + lane*8]);
#pragma unroll
    for (int c=0;c<4;c++){
      int ct = wn*4+c;
      short8v bh = *reinterpret_cast<const short8v*>(&smem[buf][(8+ct*2)*512 + lane*8]);
      short8v bl = *reinterpret_cast<const short8v*>(&smem[buf][(9+ct*2)*512 + lane*8]);
#pragma unroll
      for (int r=0;r<4;r++){
        acc[r][c] = __builtin_amdgcn_mfma_f32_16x16x32_bf16(a[r], bh, acc[r][c], 0,0,0);
        acc[r][c] = __builtin_amdgcn_mfma_f32_16x16x32_bf16(a[r], bl, acc[r][c], 0,0,0);
      }
    }
    __syncthreads();
  }

  float attv[4];
#pragma unroll
  for (int c=0;c<4;c++) attv[c] = att[bn0 + (wn*4+c)*16 + l15];
  int head = (bn0>>6) + wn;
#pragma unroll
  for (int r=0;r<4;r++){
    int rowb = brow + wm*64 + r*16 + kq*4;
#pragma unroll
    for (int j=0;j<4;j++){
      size_t rw = (size_t)(rowb + j)*HD;
#pragma unroll
      for (int c=0;c<4;c++)
        C[rw + bn0 + (wn*4+c)*16 + l15] = f2bf(acc[r][c][j]);
    }
#pragma unroll
    for (int j=0;j<4;j++){
      float p = acc[r][0][j]*attv[0] + acc[r][1][j]*attv[1]
              + acc[r][2][j]*attv[2] + acc[r][3][j]*attv[3];
      p += __shfl_xor(p, 1, 64);
      p += __shfl_xor(p, 2, 64);
      p += __shfl_xor(p, 4, 64);
      p += __shfl_xor(p, 8, 64);
      if (l15 == 0){
        float lg = p > 0.f ? p : 0.2f*p;
        alpha[(size_t)(rowb + j)*4 + head] = lg;
      }
    }
  }
}

// ---- layer-0 GAT message: gathers GT rows via n_ids-remapped sources ----
__global__ __launch_bounds__(128) void gat_msg0(
    const ushort_t* __restrict__ GT_b, const float* __restrict__ alphaG_b,
    const int* __restrict__ n_ids, const int* __restrict__ esrc_b,
    const float* __restrict__ bsum_b, uint32_t* __restrict__ g0_u)
{
  int i = blockIdx.y, d = blockIdx.x, t = threadIdx.x;
  const ushort_t* GT = GT_b + (size_t)i*IN_SZ*HD;
  const float* alphaG = alphaG_b + (size_t)i*IN_SZ*4;
  const float* bsum = bsum_b + i*HD;
  __shared__ int src[16];
  __shared__ float aw[16][4];
  if (t < 16) src[t] = n_ids[(size_t)i*N0 + esrc_b[(size_t)i*E0 + d*16 + t]];
  __syncthreads();
  if (t < 64){
    int e = t&15, h = t>>4;
    float l = alphaG[(size_t)src[e]*4 + h];
    float m = l;
#pragma unroll
    for (int off=1; off<16; off<<=1) m = fmaxf(m, __shfl_xor(m, off, 64));
    float ex = expf(l - m);
    float s = ex;
#pragma unroll
    for (int off=1; off<16; off<<=1) s += __shfl_xor(s, off, 64);
    aw[e][h] = ex / (s + 1e-16f);
  }
  __syncthreads();
  int h = t >> 5;
  float a0=0.f, a1=0.f;
#pragma unroll
  for (int e=0;e<16;e++){
    uint32_t u = *reinterpret_cast<const uint32_t*>(GT + (size_t)src[e]*HD + 2*t);
    float w = aw[e][h];
    a0 = fmaf(w, bf2f((ushort_t)(u & 0xffffu)), a0);
    a1 = fmaf(w, bf2f((ushort_t)(u >> 16)), a1);
  }
  float v0 = a0 + bsum[2*t], v1 = a1 + bsum[2*t+1];
  g0_u[((size_t)i*N1 + d)*128 + t] = (uint32_t)f2bf(v0) | ((uint32_t)f2bf(v1)<<16);
}

// ---- layer-1 GAT message: fused gate + accumulate over modalities -> xmod fp32 ----
__global__ __launch_bounds__(128) void gat_msg1(
    const ushort_t* __restrict__ xl1hi, const float* __restrict__ alpha1,
    const int* __restrict__ e1src, const float* __restrict__ gat_b,
    const uint32_t* __restrict__ g0_u, const float* __restrict__ coef,
    float* __restrict__ xmod)
{
  int d = blockIdx.x, t = threadIdx.x;
  __shared__ int src[16];
  __shared__ float aw[16][4];
  float o0 = 0.f, o1 = 0.f;
  for (int i=0;i<NM;i++){
    if (t < 16) src[t] = e1src[(size_t)i*E1 + d*16 + t];
    __syncthreads();
    if (t < 64){
      int e = t&15, h = t>>4;
      float l = alpha1[((size_t)i*N1 + src[e])*4 + h];
      float m = l;
#pragma unroll
      for (int off=1; off<16; off<<=1) m = fmaxf(m, __shfl_xor(m, off, 64));
      float ex = expf(l - m);
      float s = ex;
#pragma unroll
      for (int off=1; off<16; off<<=1) s += __shfl_xor(s, off, 64);
      aw[e][h] = ex / (s + 1e-16f);
    }
    __syncthreads();
    const ushort_t* xl = xl1hi + (size_t)i*N1*HD;
    int h = t >> 5;
    float a0=0.f, a1=0.f;
#pragma unroll
    for (int e=0;e<16;e++){
      uint32_t u = *reinterpret_cast<const uint32_t*>(xl + (size_t)src[e]*HD + 2*t);
      float w = aw[e][h];
      a0 = fmaf(w, bf2f((ushort_t)(u & 0xffffu)), a0);
      a1 = fmaf(w, bf2f((ushort_t)(u >> 16)), a1);
    }
    uint32_t gh = g0_u[((size_t)i*N1 + d)*128 + t];
    float g00 = bf2f((ushort_t)(gh & 0xffffu));
    float g01 = bf2f((ushort_t)(gh >> 16));
    const float* bias = gat_b + i*HD;
    float cv = coef[d*3 + i];
    o0 += cv*(2.f*g00 + 2.f*(a0 + bias[2*t]));
    o1 += cv*(2.f*g01 + 2.f*(a1 + bias[2*t+1]));
    __syncthreads();
  }
  *reinterpret_cast<float2*>(&xmod[(size_t)d*HD + 2*t]) = make_float2(o0, o1);
}

// ---- emb_W transpose [128,256]->[256,128] ----
__global__ void transp_embW(const float* __restrict__ w, float* __restrict__ wt)
{
  int g = blockIdx.x*256 + threadIdx.x;
  int j = g >> 8, k = g & 255;
  wt[k*128 + j] = w[g];
}

// ---- emb = xmod @ embW^T + b; writes fp32 + hi/lo bf16 ----
__global__ __launch_bounds__(256) void emb_gemm(
  const float* __restrict__ xmod, const float* __restrict__ wT,
  const float* __restrict__ eb, float* __restrict__ emb,
  ushort_t* __restrict__ ehi, ushort_t* __restrict__ elo)
{
  __shared__ float xs[32][260];
  int t = threadIdx.x;
  int brow = blockIdx.x * 32;
#pragma unroll
  for (int j=0;j<8;j++){
    int linear = j*256+t;
    int row = linear >> 6;
    int kq = linear & 63;
    float4 f = *reinterpret_cast<const float4*>(&xmod[(size_t)(brow+row)*256 + kq*4]);
    xs[row][kq*4+0]=f.x; xs[row][kq*4+1]=f.y; xs[row][kq*4+2]=f.z; xs[row][kq*4+3]=f.w;
  }
  __syncthreads();
  int tj = t & 127, th = t >> 7;
  float acc[16];
#pragma unroll
  for(int r=0;r<16;r++) acc[r]=0.f;
  for (int k=0;k<256;k++){
    float w = wT[k*128 + tj];
#pragma unroll
    for (int r=0;r<16;r++) acc[r] = fmaf(xs[th*16+r][k], w, acc[r]);
  }
  float bias = eb[tj];
#pragma unroll
  for (int r=0;r<16;r++){
    size_t idx = (size_t)(brow+th*16+r)*128 + tj;
    float v = acc[r] + bias;
    emb[idx] = v;
    ushort_t hb = f2bf(v);
    ehi[idx] = hb;
    elo[idx] = f2bf(v - bf2f(hb));
  }
}

// ---- dot = emb @ emb^T via MFMA, 3-term split ----
__global__ __launch_bounds__(256) void dot_mfma(
    const ushort_t* __restrict__ Ehi, const ushort_t* __restrict__ Elo,
    float* __restrict__ dot)
{
  __shared__ __align__(16) ushort_t lb[2][16384];
  int t = threadIdx.x, wave = t>>6, lane = t&63;
  int arow0 = blockIdx.y*128, brow0 = blockIdx.x*128;
  {
    const ushort_t* srcp = (t<128) ? Ehi : Elo;
    ushort_t* dstb = lb[(t<128)?0:1];
    int o = t & 127;
    const ushort_t* rp = srcp + (size_t)(brow0+o)*128;
#pragma unroll
    for (int g=0; g<16; g++){
      short8v v = *reinterpret_cast<const short8v*>(rp + g*8);
      int c = g>>2, grp = g&3;
      int lidx = c*4096 + (o>>4)*512 + ((grp<<4)|(o&15))*8;
      *reinterpret_cast<short8v*>(&dstb[lidx]) = v;
    }
  }
  __syncthreads();

  floatx4 acc[2][8];
#pragma unroll
  for (int rt=0;rt<2;rt++)
#pragma unroll
    for (int ot=0;ot<8;ot++) acc[rt][ot] = (floatx4){0.f,0.f,0.f,0.f};

  int ar0 = arow0 + wave*32 + (lane&15);
  int ar1 = ar0 + 16;
  int koff = (lane>>4)*8;
#pragma unroll
  for (int c=0;c<4;c++){
    short8v ah0 = *reinterpret_cast<const short8v*>(Ehi + (size_t)ar0*128 + c*32 + koff);
    short8v ah1 = *reinterpret_cast<const short8v*>(Ehi + (size_t)ar1*128 + c*32 + koff);
    short8v al0 = *reinterpret_cast<const short8v*>(Elo + (size_t)ar0*128 + c*32 + koff);
    short8v al1 = *reinterpret_cast<const short8v*>(Elo + (size_t)ar1*128 + c*32 + koff);
#pragma unroll
    for (int ot=0;ot<8;ot++){
      short8v bh = *reinterpret_cast<const short8v*>(&lb[0][c*4096 + ot*512 + lane*8]);
      short8v bl = *reinterpret_cast<const short8v*>(&lb[1][c*4096 + ot*512 + lane*8]);
      acc[0][ot] = __builtin_amdgcn_mfma_f32_16x16x32_bf16(ah0, bh, acc[0][ot], 0,0,0);
      acc[0][ot] = __builtin_amdgcn_mfma_f32_16x16x32_bf16(ah0, bl, acc[0][ot], 0,0,0);
      acc[0][ot] = __builtin_amdgcn_mfma_f32_16x16x32_bf16(al0, bh, acc[0][ot], 0,0,0);
      acc[1][ot] = __builtin_amdgcn_mfma_f32_16x16x32_bf16(ah1, bh, acc[1][ot], 0,0,0);
      acc[1][ot] = __builtin_amdgcn_mfma_f32_16x16x32_bf16(ah1, bl, acc[1][ot], 0,0,0);
      acc[1][ot] = __builtin_amdgcn_mfma_f32_16x16x32_bf16(al1, bh, acc[1][ot], 0,0,0);
    }
  }
#pragma unroll
  for (int rt=0;rt<2;rt++){
    int rb = arow0 + wave*32 + rt*16 + (lane>>4)*4;
#pragma unroll
    for (int r=0;r<4;r++)
#pragma unroll
      for (int ot=0;ot<8;ot++)
        dot[(size_t)(rb+r)*4096 + brow0 + ot*16 + (lane&15)] = acc[rt][ot][r];
  }
}

extern "C" void kernel_launch(void* const* d_in, const int* in_sizes, int n_in,
                              void* d_out, int out_size, void* d_ws, size_t ws_size,
                              hipStream_t stream) {
  (void)in_sizes; (void)n_in; (void)out_size; (void)ws_size;
  const float* masks   = (const float*)d_in[0];
  const int*   n_ids   = (const int*)d_in[1];
  const int*   e0_src  = (const int*)d_in[2];
  const int*   e1_src  = (const int*)d_in[4];
  const float* pre_W   = (const float*)d_in[6];
  const float* pre_b   = (const float*)d_in[7];
  const float* gat_W   = (const float*)d_in[8];
  const float* gat_att = (const float*)d_in[9];
  const float* gat_b   = (const float*)d_in[10];
  const float* sp      = (const float*)d_in[11];
  const float* emb_W   = (const float*)d_in[12];
  const float* emb_b   = (const float*)d_in[13];

  float* out = (float*)d_out;
  float* dot = out;                         // [4096*4096]
  float* emb = out + (size_t)NB*NB;         // [4096*128]
  float* scales_out = emb + (size_t)NB*128; // [3]

  char* p = (char*)d_ws;
  auto alloc = [&](size_t bytes)->char*{ char* r = p; p += (bytes + 255) & ~(size_t)255; return r; };
  ushort_t* GT    = (ushort_t*)alloc((size_t)NM*IN_SZ*HD*2);
  float*    alphG = (float*)alloc((size_t)NM*IN_SZ*4*4);
  uint32_t* g0u   = (uint32_t*)alloc((size_t)NM*N1*HD*2);
  ushort_t* xl1hi = (ushort_t*)alloc((size_t)NM*N1*HD*2);
  float*    alph1 = (float*)alloc((size_t)NM*N1*4*4);
  float*    xmod  = (float*)alloc((size_t)NB*HD*4);
  float*    coef  = (float*)alloc((size_t)NB*3*4);
  float*    wT    = (float*)alloc((size_t)HD*128*4);
  ushort_t* gWhi  = (ushort_t*)alloc((size_t)NM*HD*HD*2);
  ushort_t* gWlo  = (ushort_t*)alloc((size_t)NM*HD*HD*2);
  float*    bsum  = (float*)alloc((size_t)NM*HD*4);
  float*    batt  = (float*)alloc((size_t)NM*4*4);
  ushort_t* ehi   = (ushort_t*)alloc((size_t)NB*128*2);
  ushort_t* elo   = (ushort_t*)alloc((size_t)NB*128*2);

  interp_coef_k<<<16, 256, 0, stream>>>(masks, sp, coef, scales_out);
  transp_embW<<<128, 256, 0, stream>>>(emb_W, wT);
  split_k<<<(NM*HD*HD+255)/256, 256, 0, stream>>>(gat_W, gWhi, gWlo, NM*HD*HD);
  bias_prep_k<<<NM, 256, 0, stream>>>(pre_b, gat_W, gat_att, gat_b, bsum, batt);

  gt_gemm<<<dim3((IN_SZ+127)/128, 1, NM), 256, 0, stream>>>(
      pre_W, gWhi, gWlo, gat_att, batt, GT, alphG);
  gat_msg0<<<dim3(N1, NM), 128, 0, stream>>>(GT, alphG, n_ids, e0_src, bsum, g0u);
  gemm2<<<dim3(N1/128, 2, NM), 256, 0, stream>>>(
      (const ushort_t*)g0u, (size_t)N1*HD, gWhi, gWlo,
      xl1hi, (size_t)N1*HD, gat_att, alph1, (size_t)N1*4);
  gat_msg1<<<NB, 128, 0, stream>>>(xl1hi, alph1, e1_src, gat_b, g0u, coef, xmod);
  emb_gemm<<<NB/32, 256, 0, stream>>>(xmod, wT, emb_b, emb, ehi, elo);
  dot_mfma<<<dim3(32,32), 256, 0, stream>>>(ehi, elo, dot);
}

// Round 7
// 297.824 us; speedup vs baseline: 1.0667x; 1.0667x over previous
//
#include <hip/hip_runtime.h>
#include <hip/hip_bf16.h>
#include <cstdint>

#define IN_SZ 50000
#define NM 3
#define N0 40960
#define N1 16384
#define NB 4096
#define HD 256
#define DEG 16
#define E0 (N1*DEG)
#define E1 (NB*DEG)

using short8v = __attribute__((ext_vector_type(8))) short;
using floatx4 = __attribute__((ext_vector_type(4))) float;
typedef unsigned short ushort_t;

__device__ __forceinline__ ushort_t f2bf(float f){
  uint32_t u = __float_as_uint(f);
  uint32_t r = u + 0x7FFFu + ((u>>16)&1u);
  return (ushort_t)(r>>16);
}
__device__ __forceinline__ float bf2f(ushort_t h){
  return __uint_as_float(((uint32_t)h)<<16);
}
__device__ __forceinline__ void gload_lds16(const ushort_t* g, ushort_t* l){
  __builtin_amdgcn_global_load_lds(
      (const __attribute__((address_space(1))) void*)g,
      (__attribute__((address_space(3))) void*)l, 16, 0, 0);
}

// ---------------- threefry2x32 (JAX-exact) ----------------
__device__ __forceinline__ uint32_t rotl32(uint32_t x, uint32_t d){ return (x<<d)|(x>>(32u-d)); }

__device__ void tf2x32(uint32_t k0, uint32_t k1, uint32_t c0, uint32_t c1,
                       uint32_t& y0, uint32_t& y1)
{
  uint32_t ks2 = k0 ^ k1 ^ 0x1BD11BDAu;
  uint32_t x0 = c0 + k0, x1 = c1 + k1;
#define R4(a,b,c,d) \
  x0+=x1; x1=rotl32(x1,a); x1^=x0; \
  x0+=x1; x1=rotl32(x1,b); x1^=x0; \
  x0+=x1; x1=rotl32(x1,c); x1^=x0; \
  x0+=x1; x1=rotl32(x1,d); x1^=x0;
  R4(13,15,26,6)  x0+=k1;  x1+=ks2+1u;
  R4(17,29,16,24) x0+=ks2; x1+=k0+2u;
  R4(13,15,26,6)  x0+=k0;  x1+=k1+3u;
  R4(17,29,16,24) x0+=k1;  x1+=ks2+4u;
  R4(13,15,26,6)  x0+=ks2; x1+=k0+5u;
#undef R4
  y0=x0; y1=x1;
}

__global__ void interp_coef_k(const float* __restrict__ masks, const float* __restrict__ sp,
                              float* __restrict__ coef, float* __restrict__ scales_out)
{
  int b = blockIdx.x*256 + threadIdx.x;
  if (b >= NB) return;
  float s0=sp[0], s1=sp[1], s2=sp[2];
  float mx = fmaxf(s0,fmaxf(s1,s2));
  float e0=expf(s0-mx), e1=expf(s1-mx), e2=expf(s2-mx);
  float inv = 1.f/(e0+e1+e2);
  float sc[3] = {e0*inv, e1*inv, e2*inv};
  if (b == 0){ scales_out[0]=sc[0]; scales_out[1]=sc[1]; scales_out[2]=sc[2]; }

  uint32_t bits[3];
  uint32_t K0,K1, t0,t1;
  tf2x32(0u,42u,0u,1u,K0,K1);
  for (int i=0;i<3;i++){
    uint32_t idx = (uint32_t)(b*3+i);
    tf2x32(K0,K1,0u,idx,t0,t1);
    bits[i] = (t0 ^ t1) & 1u;
  }
  float mk[3] = {masks[b*3+0], masks[b*3+1], masks[b*3+2]};
  float msum = mk[0]+mk[1]+mk[2];
  float rs = (float)(bits[0]+bits[1]+bits[2]);
  float add = powf(1.f/(1.f+rs), 20.f) + powf(1.f/msum, 20.f);
  float lg[3]; float lmax = -1e30f;
  for (int i=0;i<3;i++){
    float rm = floorf((float)bits[i] + add);
    rm = rm/(rm+1e-10f);
    float mm = mk[i]*rm;
    lg[i] = mm + (1.f-mm)*(-1e10f);
    lmax = fmaxf(lmax, lg[i]);
  }
  float es[3], ssum=0.f;
  for (int i=0;i<3;i++){ es[i]=expf(lg[i]-lmax); ssum+=es[i]; }
  for (int i=0;i<3;i++) coef[b*3+i] = sc[i]*es[i]/ssum;
}

// ---- elementwise hi/lo split (gat_W) ----
__global__ void split_k(const float* __restrict__ src, ushort_t* __restrict__ hi,
                        ushort_t* __restrict__ lo, int n)
{
  int g = blockIdx.x*256 + threadIdx.x;
  if (g >= n) return;
  float v = src[g];
  ushort_t h = f2bf(v);
  hi[g] = h;
  lo[g] = f2bf(v - bf2f(h));
}

// ---- bias prep: bias2 = pre_b . gat_W^T; bsum = bias2 + gat_b; batt = bias2 . att (per head)
__global__ void bias_prep_k(const float* __restrict__ pre_b, const float* __restrict__ gat_W,
                            const float* __restrict__ gat_att, const float* __restrict__ gat_b,
                            float* __restrict__ bsum, float* __restrict__ batt)
{
  int i = blockIdx.x, o = threadIdx.x;
  const float* W = gat_W + (size_t)i*HD*HD + (size_t)o*HD;
  const float* b = pre_b + i*HD;
  float s = 0.f;
  for (int k=0;k<HD;k++) s = fmaf(b[k], W[k], s);
  bsum[i*HD + o] = s + gat_b[i*HD + o];
  __shared__ float red[256];
  red[o] = s * gat_att[i*HD + o];
  __syncthreads();
  if (o < 4){
    float p = 0.f;
    for (int j=0;j<64;j++) p += red[o*64 + j];
    batt[i*4 + o] = p;
  }
}

// ---- GT GEMM: GT[c,o] = sum_k preW[k,c] * gatW[o,k]; 40KB LDS -> 4 blocks/CU ----
// A (preW cols) reg-staged + transposed via LDS; B single-buffered via global_load_lds.
// Fused epilogue: alphaG[c,h] = leaky(GTacc . att + batt[h]).
__global__ __launch_bounds__(256) void gt_gemm(
    const float* __restrict__ preW_b,
    const ushort_t* __restrict__ Whi_b, const ushort_t* __restrict__ Wlo_b,
    const float* __restrict__ att_b, const float* __restrict__ batt,
    ushort_t* __restrict__ GT_b, float* __restrict__ alphaG_b)
{
  int i = blockIdx.z;
  int brow = blockIdx.x * 128;                      // c-offset
  const float* pw = preW_b + (size_t)i*HD*IN_SZ;
  const float* att = att_b + (size_t)i*HD;
  ushort_t* GT = GT_b + (size_t)i*IN_SZ*HD;
  float* alphaG = alphaG_b + (size_t)i*IN_SZ*4;

  __shared__ __align__(16) ushort_t As[4096];       // 8 rt x 64 lane x 8 = 8KB
  __shared__ __align__(16) ushort_t Bs[16384];      // 32 frag x 512 = 32KB

  int t = threadIdx.x, wave = t>>6, lane = t&63;
  int l15 = lane&15, kq = lane>>4;

  // B gload sources: fragment f = wave + 4*j -> ct=f>>1, hs=f&1
  const ushort_t* bsrc[8];
#pragma unroll
  for (int j=0;j<8;j++){
    int f = wave + 4*j, ct = f>>1, hs = f&1;
    const ushort_t* W = (hs ? Wlo_b : Whi_b) + (size_t)i*HD*HD;
    bsrc[j] = W + (size_t)(ct*16 + l15)*HD + kq*8;
  }
  // A-load assignment: thread covers (c_local, q0) and (c_local, q0+2)
  int cl0 = t & 127, q0 = t >> 7;
  int q1 = q0 + 2;
  int cg = brow + cl0; if (cg >= IN_SZ) cg = IN_SZ-1;
  int aoff0 = (cl0>>4)*512 + ((cl0&15) + q0*16)*8;
  int aoff1 = (cl0>>4)*512 + ((cl0&15) + q1*16)*8;

  floatx4 acc[2][16];
#pragma unroll
  for (int r=0;r<2;r++)
#pragma unroll
    for (int ct=0;ct<16;ct++) acc[r][ct] = (floatx4){0.f,0.f,0.f,0.f};

  // prologue: A(0) scalars into regs
  float a0f[8], a1f[8];
#pragma unroll
  for (int j=0;j<8;j++){
    a0f[j] = pw[(size_t)(q0*8+j)*IN_SZ + cg];
    a1f[j] = pw[(size_t)(q1*8+j)*IN_SZ + cg];
  }

  for (int cc=0; cc<8; cc++){
    short8v v0, v1;
#pragma unroll
    for (int j=0;j<8;j++){ v0[j] = (short)f2bf(a0f[j]); v1[j] = (short)f2bf(a1f[j]); }
    __syncthreads();                       // all waves done reading As/Bs
    int k0 = cc*32;
#pragma unroll
    for (int j=0;j<8;j++) gload_lds16(bsrc[j] + k0, &Bs[(wave+4*j)*512]);
    *reinterpret_cast<short8v*>(&As[aoff0]) = v0;
    *reinterpret_cast<short8v*>(&As[aoff1]) = v1;
    __syncthreads();                       // drains DMA + LDS writes
    if (cc < 7){
      int kn = (cc+1)*32;
#pragma unroll
      for (int j=0;j<8;j++){               // next chunk's A: overlaps with MFMAs below
        a0f[j] = pw[(size_t)(kn+q0*8+j)*IN_SZ + cg];
        a1f[j] = pw[(size_t)(kn+q1*8+j)*IN_SZ + cg];
      }
    }
    short8v a0 = *reinterpret_cast<const short8v*>(&As[(2*wave)*512 + lane*8]);
    short8v a1 = *reinterpret_cast<const short8v*>(&As[(2*wave+1)*512 + lane*8]);
#pragma unroll
    for (int ct=0;ct<16;ct++){
      short8v bh = *reinterpret_cast<const short8v*>(&Bs[(ct*2)*512 + lane*8]);
      short8v bl = *reinterpret_cast<const short8v*>(&Bs[(ct*2+1)*512 + lane*8]);
      acc[0][ct] = __builtin_amdgcn_mfma_f32_16x16x32_bf16(a0, bh, acc[0][ct], 0,0,0);
      acc[0][ct] = __builtin_amdgcn_mfma_f32_16x16x32_bf16(a0, bl, acc[0][ct], 0,0,0);
      acc[1][ct] = __builtin_amdgcn_mfma_f32_16x16x32_bf16(a1, bh, acc[1][ct], 0,0,0);
      acc[1][ct] = __builtin_amdgcn_mfma_f32_16x16x32_bf16(a1, bl, acc[1][ct], 0,0,0);
    }
  }

  // epilogue
  float attv[16];
#pragma unroll
  for (int ct=0;ct<16;ct++) attv[ct] = att[ct*16 + l15];
#pragma unroll
  for (int r=0;r<2;r++){
    int rbase = brow + (2*wave+r)*16 + kq*4;
#pragma unroll
    for (int j=0;j<4;j++){
      int c = rbase + j;
      bool ok = c < IN_SZ;
      size_t rw = (size_t)c*HD;
      if (ok){
#pragma unroll
        for (int ct=0;ct<16;ct++) GT[rw + ct*16 + l15] = f2bf(acc[r][ct][j]);
      }
#pragma unroll
      for (int h=0;h<4;h++){
        float p = acc[r][4*h+0][j]*attv[4*h+0] + acc[r][4*h+1][j]*attv[4*h+1]
                + acc[r][4*h+2][j]*attv[4*h+2] + acc[r][4*h+3][j]*attv[4*h+3];
        p += __shfl_xor(p, 1, 64);
        p += __shfl_xor(p, 2, 64);
        p += __shfl_xor(p, 4, 64);
        p += __shfl_xor(p, 8, 64);
        if (l15 == 0 && ok){
          p += batt[i*4 + h];
          alphaG[(size_t)c*4 + h] = p > 0.f ? p : 0.2f*p;
        }
      }
    }
  }
}

// ---- MFMA GEMM (layer 1): 128x128 tile, 2-term; fused leaky'd alpha epilogue ----
__global__ __launch_bounds__(256) void gemm2(
    const ushort_t* __restrict__ A_b, size_t a_stride,
    const ushort_t* __restrict__ Whi_b, const ushort_t* __restrict__ Wlo_b,
    ushort_t* __restrict__ C_b, size_t c_stride,
    const float* __restrict__ att_b, float* __restrict__ alpha_b, size_t al_stride)
{
  int i = blockIdx.z;
  int bn0 = blockIdx.y * 128;
  int brow = blockIdx.x * 128;
  const ushort_t* A = A_b + (size_t)i*a_stride;
  const ushort_t* Whi = Whi_b + (size_t)i*HD*HD;
  const ushort_t* Wlo = Wlo_b + (size_t)i*HD*HD;
  ushort_t* C = C_b + (size_t)i*c_stride;
  const float* att = att_b + (size_t)i*HD;
  float* alpha = alpha_b + (size_t)i*al_stride;

  __shared__ __align__(16) ushort_t smem[2][24*512];
  int t = threadIdx.x, wave = t>>6, lane = t&63;
  int l15 = lane&15, kq = lane>>4;

  int row0 = brow + wave*16 + l15;
  int row1 = brow + (wave+4)*16 + l15;

  const ushort_t* gsrc[6];
  gsrc[0] = A + (size_t)row0*HD + kq*8;
  gsrc[1] = A + (size_t)row1*HD + kq*8;
#pragma unroll
  for (int j=2;j<6;j++){
    int idx = wave + 4*(j-2);
    int ct = idx>>1, h = idx&1;
    const ushort_t* W = h ? Wlo : Whi;
    gsrc[j] = W + (size_t)(bn0 + ct*16 + l15)*HD + kq*8;
  }

  floatx4 acc[4][4];
#pragma unroll
  for (int r=0;r<4;r++)
#pragma unroll
    for (int c=0;c<4;c++) acc[r][c] = (floatx4){0.f,0.f,0.f,0.f};

  int wm = wave>>1, wn = wave&1;

#pragma unroll
  for (int j=0;j<6;j++)
    gload_lds16(gsrc[j], &smem[0][(wave + 4*j)*512]);
  __syncthreads();

  for (int cc=0; cc<8; cc++){
    int buf = cc & 1;
    if (cc < 7){
      int k0 = (cc+1)*32;
#pragma unroll
      for (int j=0;j<6;j++)
        gload_lds16(gsrc[j] + k0, &smem[buf^1][(wave + 4*j)*512]);
    }
    short8v a[4];
#pragma unroll
    for (int r=0;r<4;r++)
      a[r] = *reinterpret_cast<const short8v*>(&smem[buf][(wm*4+r)*512 + lane*8]);
#pragma unroll
    for (int c=0;c<4;c++){
      int ct = wn*4+c;
      short8v bh = *reinterpret_cast<const short8v*>(&smem[buf][(8+ct*2)*512 + lane*8]);
      short8v bl = *reinterpret_cast<const short8v*>(&smem[buf][(9+ct*2)*512 + lane*8]);
#pragma unroll
      for (int r=0;r<4;r++){
        acc[r][c] = __builtin_amdgcn_mfma_f32_16x16x32_bf16(a[r], bh, acc[r][c], 0,0,0);
        acc[r][c] = __builtin_amdgcn_mfma_f32_16x16x32_bf16(a[r], bl, acc[r][c], 0,0,0);
      }
    }
    __syncthreads();
  }

  float attv[4];
#pragma unroll
  for (int c=0;c<4;c++) attv[c] = att[bn0 + (wn*4+c)*16 + l15];
  int head = (bn0>>6) + wn;
#pragma unroll
  for (int r=0;r<4;r++){
    int rowb = brow + wm*64 + r*16 + kq*4;
#pragma unroll
    for (int j=0;j<4;j++){
      size_t rw = (size_t)(rowb + j)*HD;
#pragma unroll
      for (int c=0;c<4;c++)
        C[rw + bn0 + (wn*4+c)*16 + l15] = f2bf(acc[r][c][j]);
    }
#pragma unroll
    for (int j=0;j<4;j++){
      float p = acc[r][0][j]*attv[0] + acc[r][1][j]*attv[1]
              + acc[r][2][j]*attv[2] + acc[r][3][j]*attv[3];
      p += __shfl_xor(p, 1, 64);
      p += __shfl_xor(p, 2, 64);
      p += __shfl_xor(p, 4, 64);
      p += __shfl_xor(p, 8, 64);
      if (l15 == 0){
        float lg = p > 0.f ? p : 0.2f*p;
        alpha[(size_t)(rowb + j)*4 + head] = lg;
      }
    }
  }
}

// ---- layer-0 GAT message: gathers GT rows via n_ids-remapped sources ----
__global__ __launch_bounds__(128) void gat_msg0(
    const ushort_t* __restrict__ GT_b, const float* __restrict__ alphaG_b,
    const int* __restrict__ n_ids, const int* __restrict__ esrc_b,
    const float* __restrict__ bsum_b, uint32_t* __restrict__ g0_u)
{
  int i = blockIdx.y, d = blockIdx.x, t = threadIdx.x;
  const ushort_t* GT = GT_b + (size_t)i*IN_SZ*HD;
  const float* alphaG = alphaG_b + (size_t)i*IN_SZ*4;
  const float* bsum = bsum_b + i*HD;
  __shared__ int src[16];
  __shared__ float aw[16][4];
  if (t < 16) src[t] = n_ids[(size_t)i*N0 + esrc_b[(size_t)i*E0 + d*16 + t]];
  __syncthreads();
  if (t < 64){
    int e = t&15, h = t>>4;
    float l = alphaG[(size_t)src[e]*4 + h];
    float m = l;
#pragma unroll
    for (int off=1; off<16; off<<=1) m = fmaxf(m, __shfl_xor(m, off, 64));
    float ex = expf(l - m);
    float s = ex;
#pragma unroll
    for (int off=1; off<16; off<<=1) s += __shfl_xor(s, off, 64);
    aw[e][h] = ex / (s + 1e-16f);
  }
  __syncthreads();
  int h = t >> 5;
  float a0=0.f, a1=0.f;
#pragma unroll
  for (int e=0;e<16;e++){
    uint32_t u = *reinterpret_cast<const uint32_t*>(GT + (size_t)src[e]*HD + 2*t);
    float w = aw[e][h];
    a0 = fmaf(w, bf2f((ushort_t)(u & 0xffffu)), a0);
    a1 = fmaf(w, bf2f((ushort_t)(u >> 16)), a1);
  }
  float v0 = a0 + bsum[2*t], v1 = a1 + bsum[2*t+1];
  g0_u[((size_t)i*N1 + d)*128 + t] = (uint32_t)f2bf(v0) | ((uint32_t)f2bf(v1)<<16);
}

// ---- layer-1 GAT message: fused gate + accumulate over modalities -> xmod fp32 ----
__global__ __launch_bounds__(128) void gat_msg1(
    const ushort_t* __restrict__ xl1hi, const float* __restrict__ alpha1,
    const int* __restrict__ e1src, const float* __restrict__ gat_b,
    const uint32_t* __restrict__ g0_u, const float* __restrict__ coef,
    float* __restrict__ xmod)
{
  int d = blockIdx.x, t = threadIdx.x;
  __shared__ int src[16];
  __shared__ float aw[16][4];
  float o0 = 0.f, o1 = 0.f;
  for (int i=0;i<NM;i++){
    if (t < 16) src[t] = e1src[(size_t)i*E1 + d*16 + t];
    __syncthreads();
    if (t < 64){
      int e = t&15, h = t>>4;
      float l = alpha1[((size_t)i*N1 + src[e])*4 + h];
      float m = l;
#pragma unroll
      for (int off=1; off<16; off<<=1) m = fmaxf(m, __shfl_xor(m, off, 64));
      float ex = expf(l - m);
      float s = ex;
#pragma unroll
      for (int off=1; off<16; off<<=1) s += __shfl_xor(s, off, 64);
      aw[e][h] = ex / (s + 1e-16f);
    }
    __syncthreads();
    const ushort_t* xl = xl1hi + (size_t)i*N1*HD;
    int h = t >> 5;
    float a0=0.f, a1=0.f;
#pragma unroll
    for (int e=0;e<16;e++){
      uint32_t u = *reinterpret_cast<const uint32_t*>(xl + (size_t)src[e]*HD + 2*t);
      float w = aw[e][h];
      a0 = fmaf(w, bf2f((ushort_t)(u & 0xffffu)), a0);
      a1 = fmaf(w, bf2f((ushort_t)(u >> 16)), a1);
    }
    uint32_t gh = g0_u[((size_t)i*N1 + d)*128 + t];
    float g00 = bf2f((ushort_t)(gh & 0xffffu));
    float g01 = bf2f((ushort_t)(gh >> 16));
    const float* bias = gat_b + i*HD;
    float cv = coef[d*3 + i];
    o0 += cv*(2.f*g00 + 2.f*(a0 + bias[2*t]));
    o1 += cv*(2.f*g01 + 2.f*(a1 + bias[2*t+1]));
    __syncthreads();
  }
  *reinterpret_cast<float2*>(&xmod[(size_t)d*HD + 2*t]) = make_float2(o0, o1);
}

// ---- emb_W transpose [128,256]->[256,128] ----
__global__ void transp_embW(const float* __restrict__ w, float* __restrict__ wt)
{
  int g = blockIdx.x*256 + threadIdx.x;
  int j = g >> 8, k = g & 255;
  wt[k*128 + j] = w[g];
}

// ---- emb = xmod @ embW^T + b; writes fp32 + hi/lo bf16 ----
__global__ __launch_bounds__(256) void emb_gemm(
  const float* __restrict__ xmod, const float* __restrict__ wT,
  const float* __restrict__ eb, float* __restrict__ emb,
  ushort_t* __restrict__ ehi, ushort_t* __restrict__ elo)
{
  __shared__ float xs[32][260];
  int t = threadIdx.x;
  int brow = blockIdx.x * 32;
#pragma unroll
  for (int j=0;j<8;j++){
    int linear = j*256+t;
    int row = linear >> 6;
    int kq = linear & 63;
    float4 f = *reinterpret_cast<const float4*>(&xmod[(size_t)(brow+row)*256 + kq*4]);
    xs[row][kq*4+0]=f.x; xs[row][kq*4+1]=f.y; xs[row][kq*4+2]=f.z; xs[row][kq*4+3]=f.w;
  }
  __syncthreads();
  int tj = t & 127, th = t >> 7;
  float acc[16];
#pragma unroll
  for(int r=0;r<16;r++) acc[r]=0.f;
  for (int k=0;k<256;k++){
    float w = wT[k*128 + tj];
#pragma unroll
    for (int r=0;r<16;r++) acc[r] = fmaf(xs[th*16+r][k], w, acc[r]);
  }
  float bias = eb[tj];
#pragma unroll
  for (int r=0;r<16;r++){
    size_t idx = (size_t)(brow+th*16+r)*128 + tj;
    float v = acc[r] + bias;
    emb[idx] = v;
    ushort_t hb = f2bf(v);
    ehi[idx] = hb;
    elo[idx] = f2bf(v - bf2f(hb));
  }
}

// ---- dot = emb @ emb^T via MFMA, 3-term split ----
__global__ __launch_bounds__(256) void dot_mfma(
    const ushort_t* __restrict__ Ehi, const ushort_t* __restrict__ Elo,
    float* __restrict__ dot)
{
  __shared__ __align__(16) ushort_t lb[2][16384];
  int t = threadIdx.x, wave = t>>6, lane = t&63;
  int arow0 = blockIdx.y*128, brow0 = blockIdx.x*128;
  {
    const ushort_t* srcp = (t<128) ? Ehi : Elo;
    ushort_t* dstb = lb[(t<128)?0:1];
    int o = t & 127;
    const ushort_t* rp = srcp + (size_t)(brow0+o)*128;
#pragma unroll
    for (int g=0; g<16; g++){
      short8v v = *reinterpret_cast<const short8v*>(rp + g*8);
      int c = g>>2, grp = g&3;
      int lidx = c*4096 + (o>>4)*512 + ((grp<<4)|(o&15))*8;
      *reinterpret_cast<short8v*>(&dstb[lidx]) = v;
    }
  }
  __syncthreads();

  floatx4 acc[2][8];
#pragma unroll
  for (int rt=0;rt<2;rt++)
#pragma unroll
    for (int ot=0;ot<8;ot++) acc[rt][ot] = (floatx4){0.f,0.f,0.f,0.f};

  int ar0 = arow0 + wave*32 + (lane&15);
  int ar1 = ar0 + 16;
  int koff = (lane>>4)*8;
#pragma unroll
  for (int c=0;c<4;c++){
    short8v ah0 = *reinterpret_cast<const short8v*>(Ehi + (size_t)ar0*128 + c*32 + koff);
    short8v ah1 = *reinterpret_cast<const short8v*>(Ehi + (size_t)ar1*128 + c*32 + koff);
    short8v al0 = *reinterpret_cast<const short8v*>(Elo + (size_t)ar0*128 + c*32 + koff);
    short8v al1 = *reinterpret_cast<const short8v*>(Elo + (size_t)ar1*128 + c*32 + koff);
#pragma unroll
    for (int ot=0;ot<8;ot++){
      short8v bh = *reinterpret_cast<const short8v*>(&lb[0][c*4096 + ot*512 + lane*8]);
      short8v bl = *reinterpret_cast<const short8v*>(&lb[1][c*4096 + ot*512 + lane*8]);
      acc[0][ot] = __builtin_amdgcn_mfma_f32_16x16x32_bf16(ah0, bh, acc[0][ot], 0,0,0);
      acc[0][ot] = __builtin_amdgcn_mfma_f32_16x16x32_bf16(ah0, bl, acc[0][ot], 0,0,0);
      acc[0][ot] = __builtin_amdgcn_mfma_f32_16x16x32_bf16(al0, bh, acc[0][ot], 0,0,0);
      acc[1][ot] = __builtin_amdgcn_mfma_f32_16x16x32_bf16(ah1, bh, acc[1][ot], 0,0,0);
      acc[1][ot] = __builtin_amdgcn_mfma_f32_16x16x32_bf16(ah1, bl, acc[1][ot], 0,0,0);
      acc[1][ot] = __builtin_amdgcn_mfma_f32_16x16x32_bf16(al1, bh, acc[1][ot], 0,0,0);
    }
  }
#pragma unroll
  for (int rt=0;rt<2;rt++){
    int rb = arow0 + wave*32 + rt*16 + (lane>>4)*4;
#pragma unroll
    for (int r=0;r<4;r++)
#pragma unroll
      for (int ot=0;ot<8;ot++)
        dot[(size_t)(rb+r)*4096 + brow0 + ot*16 + (lane&15)] = acc[rt][ot][r];
  }
}

extern "C" void kernel_launch(void* const* d_in, const int* in_sizes, int n_in,
                              void* d_out, int out_size, void* d_ws, size_t ws_size,
                              hipStream_t stream) {
  (void)in_sizes; (void)n_in; (void)out_size; (void)ws_size;
  const float* masks   = (const float*)d_in[0];
  const int*   n_ids   = (const int*)d_in[1];
  const int*   e0_src  = (const int*)d_in[2];
  const int*   e1_src  = (const int*)d_in[4];
  const float* pre_W   = (const float*)d_in[6];
  const float* pre_b   = (const float*)d_in[7];
  const float* gat_W   = (const float*)d_in[8];
  const float* gat_att = (const float*)d_in[9];
  const float* gat_b   = (const float*)d_in[10];
  const float* sp      = (const float*)d_in[11];
  const float* emb_W   = (const float*)d_in[12];
  const float* emb_b   = (const float*)d_in[13];

  float* out = (float*)d_out;
  float* dot = out;                         // [4096*4096]
  float* emb = out + (size_t)NB*NB;         // [4096*128]
  float* scales_out = emb + (size_t)NB*128; // [3]

  char* p = (char*)d_ws;
  auto alloc = [&](size_t bytes)->char*{ char* r = p; p += (bytes + 255) & ~(size_t)255; return r; };
  ushort_t* GT    = (ushort_t*)alloc((size_t)NM*IN_SZ*HD*2);
  float*    alphG = (float*)alloc((size_t)NM*IN_SZ*4*4);
  uint32_t* g0u   = (uint32_t*)alloc((size_t)NM*N1*HD*2);
  ushort_t* xl1hi = (ushort_t*)alloc((size_t)NM*N1*HD*2);
  float*    alph1 = (float*)alloc((size_t)NM*N1*4*4);
  float*    xmod  = (float*)alloc((size_t)NB*HD*4);
  float*    coef  = (float*)alloc((size_t)NB*3*4);
  float*    wT    = (float*)alloc((size_t)HD*128*4);
  ushort_t* gWhi  = (ushort_t*)alloc((size_t)NM*HD*HD*2);
  ushort_t* gWlo  = (ushort_t*)alloc((size_t)NM*HD*HD*2);
  float*    bsum  = (float*)alloc((size_t)NM*HD*4);
  float*    batt  = (float*)alloc((size_t)NM*4*4);
  ushort_t* ehi   = (ushort_t*)alloc((size_t)NB*128*2);
  ushort_t* elo   = (ushort_t*)alloc((size_t)NB*128*2);

  interp_coef_k<<<16, 256, 0, stream>>>(masks, sp, coef, scales_out);
  transp_embW<<<128, 256, 0, stream>>>(emb_W, wT);
  split_k<<<(NM*HD*HD+255)/256, 256, 0, stream>>>(gat_W, gWhi, gWlo, NM*HD*HD);
  bias_prep_k<<<NM, 256, 0, stream>>>(pre_b, gat_W, gat_att, gat_b, bsum, batt);

  gt_gemm<<<dim3((IN_SZ+127)/128, 1, NM), 256, 0, stream>>>(
      pre_W, gWhi, gWlo, gat_att, batt, GT, alphG);
  gat_msg0<<<dim3(N1, NM), 128, 0, stream>>>(GT, alphG, n_ids, e0_src, bsum, g0u);
  gemm2<<<dim3(N1/128, 2, NM), 256, 0, stream>>>(
      (const ushort_t*)g0u, (size_t)N1*HD, gWhi, gWlo,
      xl1hi, (size_t)N1*HD, gat_att, alph1, (size_t)N1*4);
  gat_msg1<<<NB, 128, 0, stream>>>(xl1hi, alph1, e1_src, gat_b, g0u, coef, xmod);
  emb_gemm<<<NB/32, 256, 0, stream>>>(xmod, wT, emb_b, emb, ehi, elo);
  dot_mfma<<<dim3(32,32), 256, 0, stream>>>(ehi, elo, dot);
}